// Round 1
// baseline (673.415 us; speedup 1.0000x reference)
//
#include <hip/hip_runtime.h>

// Adaptive avg pool 64x64 -> 6x6, fp32, N=16, C=2048 (32768 planes).
// Bin edges (compile-time): starts {0,10,21,32,42,53}, ends {11,22,32,43,54,64}
// (bins OVERLAP by one row/col at 10,21,42,53; widths 11/12).
//
// Structure: one WAVE owns a plane, zero barriers.
//   - lane l: row-group g=l>>4 (rows 16g..16g+15), float4-col c=l&15.
//   - 16 coalesced dwordx4 loads/plane (one vaddr + imm offsets t*256B).
//   - each row-group hits exactly 2 H-bins; split at local row 11/10 (g even)
//     or 6/5 (g odd) -> accumulate into 2 float4 regs, mostly unconditional.
//   - per-wave 8x68-float LDS slab (68*4B stride: 16B-aligned float4 writes,
//     reads land 2-way max on banks = free). Same-wave visibility via
//     s_waitcnt lgkmcnt(0) (DS completes in-order per wave) -- NO syncthreads.
//   - lanes 0..35 do the W-bin reduction + store; lanes 36..63 flow straight
//     into the next plane's loads.
// Grid: 1024 blocks x 256 thr = 4096 waves = 16 waves/CU resident
// (launch_bounds caps VGPR at 128), 8 planes/wave grid-stride.

#define H_IN 64
#define W_IN 64
#define H_OUT 6
#define W_OUT 6
#define SLOT_STRIDE 68      // floats; 272 B: 16B-aligned, spreads banks
#define WPB 4               // waves per block

__device__ __forceinline__ void add4(float4& d, const float4 v) {
    d.x += v.x; d.y += v.y; d.z += v.z; d.w += v.w;
}

__global__ __launch_bounds__(256, 4)
void adaptive_pool_kernel(const float* __restrict__ x,
                          float* __restrict__ out,
                          const int n_planes) {
    __shared__ float lds[WPB][8][SLOT_STRIDE];   // 8704 B / block

    const int tid  = threadIdx.x;
    const int lane = tid & 63;
    const int wid  = tid >> 6;
    const int g    = lane >> 4;          // row-group: rows 16g..16g+15
    const int c    = lane & 15;          // float4-column: cols 4c..4c+3
    const bool g_even = ((g & 1) == 0);  // split at local row 11 (even) / 6 (odd)

    float* const L = &lds[wid][0][0];

    // Loop-invariant per-lane output descriptors (lanes 0..35 = (i,j) bins).
    int sA = 0, bsj = 0, bej = 0;
    bool two = false;
    float scale = 0.f;
    if (lane < 36) {
        const int i = lane / 6;
        const int j = lane - i * 6;
        sA  = i + (i + 1) / 3;                 // H-bin -> first slot {0,1,3,4,5,7}
        two = (i == 1) || (i == 4);            // bins 1,4 span two row-groups
        bsj = (j * 64) / 6;                    // {0,10,21,32,42,53}
        bej = ((j + 1) * 64 + 5) / 6;          // {11,22,32,43,54,64}
        const int bsi = (i * 64) / 6;
        const int bei = ((i + 1) * 64 + 5) / 6;
        scale = 1.0f / (float)((bei - bsi) * (bej - bsj));
    }

    const int gw = blockIdx.x * WPB + wid;     // global wave id
    const int nw = gridDim.x * WPB;

    for (int plane = gw; plane < n_planes; plane += nw) {
        const float4* __restrict__ p4 =
            (const float4*)(x + (size_t)plane * (H_IN * W_IN)) + (g * 256 + c);

        float4 a = make_float4(0.f, 0.f, 0.f, 0.f);  // first H-bin of group
        float4 b = make_float4(0.f, 0.f, 0.f, 0.f);  // second H-bin of group

        // local row t: accA iff t < eA (eA = g_even?11:6); accB iff t >= eA-1
        #pragma unroll
        for (int t = 0; t < 16; ++t) {
            const float4 v = p4[t * 16];     // byte offset t*256: imm-foldable
            if (t < 5) {
                add4(a, v);
            } else if (t == 5) {
                add4(a, v);                  // 5 < 6 and 5 < 11
                if (!g_even) add4(b, v);     // odd: 5 >= 5
            } else if (t < 10) {
                if (g_even) add4(a, v); else add4(b, v);   // complementary
            } else if (t == 10) {
                if (g_even) add4(a, v);      // 10 < 11
                add4(b, v);                  // 10 >= 10 and 10 >= 5
            } else {
                add4(b, v);
            }
        }

        // Per-wave column sums: slot 2g = first bin part, 2g+1 = second.
        // (slots: 0=bin0, 1|2=bin1, 3=bin2, 4=bin3, 5|6=bin4, 7=bin5)
        *(float4*)&L[(2 * g    ) * SLOT_STRIDE + 4 * c] = a;
        *(float4*)&L[(2 * g + 1) * SLOT_STRIDE + 4 * c] = b;
        // Same-wave LDS visibility; "memory" clobber pins ds ops both sides.
        asm volatile("s_waitcnt lgkmcnt(0)" ::: "memory");

        if (lane < 36) {
            const float* __restrict__ pA = &L[sA * SLOT_STRIDE];
            float s = 0.f;
            for (int w = bsj; w < bej; ++w) s += pA[w];
            if (two) {                        // merge second row-group part
                const float* __restrict__ pB = pA + SLOT_STRIDE;
                for (int w = bsj; w < bej; ++w) s += pB[w];
            }
            out[(size_t)plane * (H_OUT * W_OUT) + lane] = s * scale;
        }
        // Next iteration's ds_writes are same-wave lockstep: they sit after
        // these reads in program order for all 64 lanes; no cross-wave sharing.
    }
}

extern "C" void kernel_launch(void* const* d_in, const int* in_sizes, int n_in,
                              void* d_out, int out_size, void* d_ws, size_t ws_size,
                              hipStream_t stream) {
    const float* x = (const float*)d_in[0];
    float* out = (float*)d_out;
    const int n_planes = in_sizes[0] / (H_IN * W_IN);   // 16*2048 = 32768
    adaptive_pool_kernel<<<1024, 256, 0, stream>>>(x, out, n_planes);
}